// Round 4
// baseline (212.727 us; speedup 1.0000x reference)
//
#include <hip/hip_runtime.h>
#include <stdint.h>
#include <math.h>

#define SLEN 2048
#define TOKENS_PER_OUT 8388608   // 1024*4*2048

// ---------- Threefry-2x32, 20 rounds, matches jax._src.prng ----------
__host__ __device__ __forceinline__ void tf2x32(uint32_t k0, uint32_t k1,
                                                uint32_t x0, uint32_t x1,
                                                uint32_t &o0, uint32_t &o1) {
  uint32_t ks2 = 0x1BD11BDAu ^ k0 ^ k1;
  x0 += k0; x1 += k1;
#define TFR(r) { x0 += x1; x1 = (x1 << (r)) | (x1 >> (32 - (r))); x1 ^= x0; }
  TFR(13) TFR(15) TFR(26) TFR(6)
  x0 += k1;  x1 += ks2 + 1u;
  TFR(17) TFR(29) TFR(16) TFR(24)
  x0 += ks2; x1 += k0 + 2u;
  TFR(13) TFR(15) TFR(26) TFR(6)
  x0 += k0;  x1 += k1 + 3u;
  TFR(17) TFR(29) TFR(16) TFR(24)
  x0 += k1;  x1 += ks2 + 4u;
  TFR(13) TFR(15) TFR(26) TFR(6)
  x0 += ks2; x1 += k0 + 5u;
#undef TFR
  o0 = x0; o1 = x1;
}

__device__ __forceinline__ float u01_from_bits(uint32_t bits) {
  return __uint_as_float((bits >> 9) | 0x3F800000u) - 1.0f;
}

// Correctly-rounded-quality f32 log for positive normal inputs.
// f64 atanh-form: x=2^e*m, m in [sqrt2/2,sqrt2), r=(m-1)/(m+1) (|r|<=0.1716),
// log(x)=e*ln2 + 2r*(1 + t/3 + ... + t^6/13), t=r^2. v_rcp_f64 (~2^-26) + ONE
// Newton step -> ~2^-52, at the f64 rounding floor; we only need ~2^-35 for
// the f32 final rounding to be unambiguous. Truncation rel err ~2^-39.5.
__device__ __forceinline__ float log_cr(float x) {
#pragma clang fp contract(off)
  double d = (double)x;
  long long b = __double_as_longlong(d);
  int e = (int)(b >> 52) - 1023;                 // x positive normal
  double m = __longlong_as_double((b & 0x000FFFFFFFFFFFFFLL) | 0x3FF0000000000000LL);
  if (m > 1.4142135623730951) { m *= 0.5; e += 1; }
  double mp1 = m + 1.0;
  double y = __builtin_amdgcn_rcp(mp1);          // v_rcp_f64
  y = fma(fma(-mp1, y, 1.0), y, y);              // Newton -> ~2^-52
  double r = (m - 1.0) * y;
  double t = r * r;
  double p = 0.07692307692307693;                // 1/13
  p = fma(p, t, 0.09090909090909091);            // 1/11
  p = fma(p, t, 0.1111111111111111);             // 1/9
  p = fma(p, t, 0.14285714285714285);            // 1/7
  p = fma(p, t, 0.2);                            // 1/5
  p = fma(p, t, 0.3333333333333333);             // 1/3
  double q = fma(p, t, 1.0);
  return (float)fma((double)e, 0.6931471805599453, 2.0 * (r * q));
}

// XLA ErfInv f32 expander (Giles poly), log1p per ElementalIrEmitter::EmitLog1p
__device__ float erfinv_xla(float x) {
#pragma clang fp contract(off)
  float x2  = x * x;
  float nx2 = -x2;
  float l1p;
  if (fabsf(nx2) < 1e-4f) {
    l1p = (-0.5f * nx2 + 1.0f) * nx2;
  } else {
    l1p = log_cr(1.0f + nx2);
  }
  float w = -l1p;
  float p;
  if (w < 5.0f) {
    float ww = w - 2.5f;
    p = 2.81022636e-08f;
    p = p * ww + 3.43273939e-07f;
    p = p * ww + -3.5233877e-06f;
    p = p * ww + -4.39150654e-06f;
    p = p * ww + 0.00021858087f;
    p = p * ww + -0.00125372503f;
    p = p * ww + -0.00417768164f;
    p = p * ww + 0.246640727f;
    p = p * ww + 1.50140941f;
  } else {
    float ww = sqrtf(w) - 3.0f;
    p = -0.000200214257f;
    p = p * ww + 0.000100950558f;
    p = p * ww + 0.00134934322f;
    p = p * ww + -0.00367342844f;
    p = p * ww + 0.00573950773f;
    p = p * ww + -0.0076224613f;
    p = p * ww + 0.00943887047f;
    p = p * ww + 1.00167406f;
    p = p * ww + 2.83297682f;
  }
  return p * x;
}

// One wave per row: 64 threads, ZERO __syncthreads. Lane owns 8 chunks of 4
// consecutive elems (chunk c = e*64+lane) -> perfectly coalesced float4/int4.
__global__ __launch_bounds__(64, 4)
void gumbel_topk_mask(const float* __restrict__ wfull,   // (B,C,2S) f32
                      const int*   __restrict__ attn,    // (B,C,S) i32
                      const int*   __restrict__ ids,     // (B,C,S) i32
                      int* __restrict__ out,             // 3x(B,C,S) i32 concat
                      uint32_t kg0, uint32_t kg1, uint32_t kn0, uint32_t kn1) {
#pragma clang fp contract(off)
  const int row  = blockIdx.x;
  const int lane = threadIdx.x;            // 0..63

  __shared__ __align__(16) uint32_t mk[SLEN];    // mapped keys
  __shared__ __align__(16) uint32_t hist[256];

  const size_t rbase = (size_t)row * SLEN;
  const size_t wbase = (size_t)row * (2 * SLEN);

  ((uint4*)hist)[lane] = make_uint4(0u, 0u, 0u, 0u);   // 64 lanes x 4 bins

  // ---- phase 1: keys + fused pass-3 histogram (rolled over 8 chunks) ----
  int psum = 0;
  for (int e = 0; e < 8; ++e) {
    const int c = e * 64 + lane;                       // chunk id
    float4 wv = ((const float4*)(wfull + wbase))[c];
    int4   av = ((const int4*)(attn + rbase))[c];
    psum += av.x + av.y + av.z + av.w;
    float wl[4] = {wv.x, wv.y, wv.z, wv.w};
    uint32_t mv[4];
#pragma unroll
    for (int j = 0; j < 4; ++j) {
      uint32_t o0, o1;
      tf2x32(kg0, kg1, 0u, (uint32_t)(rbase + 4 * c + j), o0, o1);
      float f  = u01_from_bits(o0 ^ o1);
      float uu = fmaxf(1.17549435e-38f, f * 1.0f + 1.17549435e-38f);
      float g  = -log_cr(-log_cr(uu));
      float key = (wl[j] > 0.0f) ? (log_cr(fmaxf(wl[j], 1e-30f)) + g)
                                 : -__builtin_inff();
      uint32_t kb = __float_as_uint(key);
      mv[j] = (kb & 0x80000000u) ? ~kb : (kb | 0x80000000u);  // monotone map
      atomicAdd(&hist[mv[j] >> 24], 1u);                      // pass-3 hist
    }
    ((uint4*)mk)[c] = make_uint4(mv[0], mv[1], mv[2], mv[3]);
  }

  // attention sum -> all lanes (butterfly)
#pragma unroll
  for (int off = 32; off; off >>= 1) psum += __shfl_xor(psum, off, 64);

  // ---- num_to_mask: all 64 lanes redundantly (uniform) ----
  int kk;
  {
    uint32_t o0, o1;
    tf2x32(kn0, kn1, 0u, (uint32_t)row, o0, o1);
    float f   = u01_from_bits(o0 ^ o1);
    float lo  = __uint_as_float(0xBF7FFFFFu);      // nextafter(-1,0)
    float u2  = fmaxf(lo, f * 2.0f + lo);          // (1-lo) rounds to 2.0f
    float z   = erfinv_xla(u2);
    float nrm = 1.4142135623730951f * z;
    float frac = 0.15f + 0.0375f * nrm;
    kk = (int)floorf((float)psum * frac);
  }

  // ---- radix-select k-th largest mapped key; all state in registers ----
  uint32_t T, r;
  if (kk <= 0)         { T = 0xFFFFFFFFu; r = 0u; }
  else if (kk >= SLEN) { T = 0u;          r = SLEN; }
  else {
    uint32_t need = (uint32_t)kk, prefix = 0u;
    for (int p = 3;; --p) {
      uint4 hq = ((const uint4*)hist)[lane];         // bins 4*lane..4*lane+3
      uint32_t hh[4] = {hq.x, hq.y, hq.z, hq.w};
      uint32_t gs  = hh[0] + hh[1] + hh[2] + hh[3];
      uint32_t sfx = gs;                             // inclusive suffix sum
#pragma unroll
      for (int off = 1; off < 64; off <<= 1) {
        uint32_t n = __shfl_down(sfx, off, 64);
        if (lane + off < 64) sfx += n;
      }
      uint32_t Gex = sfx - gs;                       // sum over lanes > me
      uint32_t SS[4];
      SS[3] = Gex;
      SS[2] = SS[3] + hh[3];
      SS[1] = SS[2] + hh[2];
      SS[0] = SS[1] + hh[1];
      int win = -1; uint32_t wrem = 0u, wcnt = 0u;
#pragma unroll
      for (int i = 0; i < 4; ++i) {
        if (hh[i] && SS[i] < need && need <= SS[i] + hh[i]) {  // unique winner
          win = 4 * lane + i; wrem = need - SS[i]; wcnt = hh[i];
        }
      }
      unsigned long long bal = __ballot(win >= 0);
      int wl_ = __ffsll(bal) - 1;
      prefix |= ((uint32_t)__shfl(win, wl_, 64)) << (8 * p);
      need = (uint32_t)__shfl((int)wrem, wl_, 64);
      uint32_t cnt = (uint32_t)__shfl((int)wcnt, wl_, 64);
      if (p == 0 || need == cnt) break;   // need==cnt: whole bin taken, low
                                          // bytes of prefix stay 0 (see epi)
      // build pass p-1 histogram (predicated)
      ((uint4*)hist)[lane] = make_uint4(0u, 0u, 0u, 0u);
      const int sh = 8 * p;
      for (int e = 0; e < 8; ++e) {
        uint4 mq = ((const uint4*)mk)[e * 64 + lane];
        uint32_t mm[4] = {mq.x, mq.y, mq.z, mq.w};
#pragma unroll
        for (int j = 0; j < 4; ++j)
          if ((mm[j] >> sh) == (prefix >> sh))
            atomicAdd(&hist[(mm[j] >> (sh - 8)) & 255u], 1u);
      }
    }
    T = prefix;
    r = need;   // take first r (by index) among keys == T; if early-exit,
                // all ==T keys are in the taken bin and #(==T) <= r. OK.
  }

  // ---- epilogue: stable tie-break via ballots, fused with stores ----
  const unsigned long long lt = (1ull << lane) - 1ull;   // lanes before me
  uint32_t total = 0u;                                   // eq in prior slots
  for (int e = 0; e < 8; ++e) {
    const int c = e * 64 + lane;
    uint4 mq = ((const uint4*)mk)[c];
    int4  iv = ((const int4*)(ids + rbase))[c];
    uint32_t mm[4] = {mq.x, mq.y, mq.z, mq.w};
    bool eq[4];
    uint32_t cross = 0u, slot_tot = 0u;
#pragma unroll
    for (int j = 0; j < 4; ++j) {
      eq[j] = (mm[j] == T);
      unsigned long long bj = __ballot(eq[j]);
      cross    += (uint32_t)__popcll(bj & lt);
      slot_tot += (uint32_t)__popcll(bj);
    }
    uint32_t excl = total + cross;       // #eq with global index < my elem 0
    total += slot_tot;
    int o_[4], m_[4], l_[4];
    int idv[4] = {iv.x, iv.y, iv.z, iv.w};
#pragma unroll
    for (int j = 0; j < 4; ++j) {
      bool msk = (mm[j] > T) || (eq[j] && (excl < r));
      excl += eq[j] ? 1u : 0u;
      o_[j] = msk ? 103 : idv[j];        // MASK_ID
      m_[j] = msk ? 1 : 0;
      l_[j] = msk ? -1 : 0;
    }
    ((int4*)(out + rbase))[c]                    = make_int4(o_[0], o_[1], o_[2], o_[3]);
    ((int4*)(out + TOKENS_PER_OUT + rbase))[c]   = make_int4(m_[0], m_[1], m_[2], m_[3]);
    ((int4*)(out + 2 * TOKENS_PER_OUT + rbase))[c] = make_int4(l_[0], l_[1], l_[2], l_[3]);
  }
}

extern "C" void kernel_launch(void* const* d_in, const int* in_sizes, int n_in,
                              void* d_out, int out_size, void* d_ws, size_t ws_size,
                              hipStream_t stream) {
  (void)n_in; (void)d_ws; (void)ws_size; (void)out_size;
  const float* wfull = (const float*)d_in[0];   // my_attention_mask (B,C,2S)
  const int*   attn  = (const int*)d_in[1];     // attention_mask    (B,C,S)
  const int*   ids   = (const int*)d_in[2];     // input_ids         (B,C,S)
  int* out = (int*)d_out;

  // jax.random.key(42) -> (0,42); partitionable split: kg=enc(key,(0,0)), kn=enc(key,(0,1))
  uint32_t kg0, kg1, kn0, kn1, o0, o1;
  tf2x32(0u, 42u, 0u, 0u, o0, o1); kg0 = o0; kg1 = o1;
  tf2x32(0u, 42u, 0u, 1u, o0, o1); kn0 = o0; kn1 = o1;

  int rows = in_sizes[1] / SLEN;                // 4096
  hipLaunchKernelGGL(gumbel_topk_mask, dim3(rows), dim3(64), 0, stream,
                     wfull, attn, ids, out, kg0, kg1, kn0, kn1);
}

// Round 5
// 207.468 us; speedup vs baseline: 1.0253x; 1.0253x over previous
//
#include <hip/hip_runtime.h>
#include <stdint.h>
#include <math.h>

#define SLEN 2048
#define EPT 8
#define NTHREADS 256
#define TOKENS_PER_OUT 8388608   // 1024*4*2048

// ---------- Threefry-2x32, 20 rounds, matches jax._src.prng ----------
// scalar version (host-side key derivation)
__host__ __device__ __forceinline__ void tf2x32(uint32_t k0, uint32_t k1,
                                                uint32_t x0, uint32_t x1,
                                                uint32_t &o0, uint32_t &o1) {
  uint32_t ks2 = 0x1BD11BDAu ^ k0 ^ k1;
  x0 += k0; x1 += k1;
#define TFR(r) { x0 += x1; x1 = (x1 << (r)) | (x1 >> (32 - (r))); x1 ^= x0; }
  TFR(13) TFR(15) TFR(26) TFR(6)
  x0 += k1;  x1 += ks2 + 1u;
  TFR(17) TFR(29) TFR(16) TFR(24)
  x0 += ks2; x1 += k0 + 2u;
  TFR(13) TFR(15) TFR(26) TFR(6)
  x0 += k0;  x1 += k1 + 3u;
  TFR(17) TFR(29) TFR(16) TFR(24)
  x0 += k1;  x1 += ks2 + 4u;
  TFR(13) TFR(15) TFR(26) TFR(6)
  x0 += ks2; x1 += k0 + 5u;
#undef TFR
  o0 = x0; o1 = x1;
}

// 4 independent threefry streams, stage-interleaved for ILP.
// counters (0, cbase+i); returns o0^o1 per stream.
__device__ __forceinline__ void tf4_bits(uint32_t k0, uint32_t k1,
                                         uint32_t cbase, uint32_t bits[4]) {
  const uint32_t ks2 = 0x1BD11BDAu ^ k0 ^ k1;
  uint32_t x0[4], x1[4];
#pragma unroll
  for (int i = 0; i < 4; ++i) { x0[i] = k0; x1[i] = (cbase + (uint32_t)i) + k1; }
#define TFR4(r)                                                         \
  _Pragma("unroll")                                                     \
  for (int i = 0; i < 4; ++i) {                                         \
    x0[i] += x1[i];                                                     \
    x1[i] = (x1[i] << (r)) | (x1[i] >> (32 - (r)));                     \
    x1[i] ^= x0[i];                                                     \
  }
#define INJ4(a, b)                                                      \
  _Pragma("unroll")                                                     \
  for (int i = 0; i < 4; ++i) { x0[i] += (a); x1[i] += (b); }
  TFR4(13) TFR4(15) TFR4(26) TFR4(6)
  INJ4(k1, ks2 + 1u)
  TFR4(17) TFR4(29) TFR4(16) TFR4(24)
  INJ4(ks2, k0 + 2u)
  TFR4(13) TFR4(15) TFR4(26) TFR4(6)
  INJ4(k0, k1 + 3u)
  TFR4(17) TFR4(29) TFR4(16) TFR4(24)
  INJ4(k1, ks2 + 4u)
  TFR4(13) TFR4(15) TFR4(26) TFR4(6)
  INJ4(ks2, k0 + 5u)
#undef TFR4
#undef INJ4
#pragma unroll
  for (int i = 0; i < 4; ++i) bits[i] = x0[i] ^ x1[i];
}

__device__ __forceinline__ float u01_from_bits(uint32_t bits) {
  return __uint_as_float((bits >> 9) | 0x3F800000u) - 1.0f;
}

// 4 correctly-rounded-quality f32 logs (positive normal inputs), stage-wise
// interleaved: dependent ops of one chain are >=4 instructions apart, so
// in-order issue hides f64 latency. Math identical to the verified scalar
// log_cr: atanh-form f64, rcp+1 Newton, 6-term even poly (rel err ~2^-39.5).
__device__ __forceinline__ void log4_cr(const float x[4], float out[4]) {
#pragma clang fp contract(off)
  double m[4]; int e[4];
#pragma unroll
  for (int i = 0; i < 4; ++i) {
    long long b = __double_as_longlong((double)x[i]);
    e[i] = (int)(b >> 52) - 1023;
    m[i] = __longlong_as_double((b & 0x000FFFFFFFFFFFFFLL) | 0x3FF0000000000000LL);
  }
#pragma unroll
  for (int i = 0; i < 4; ++i) {
    bool c = m[i] > 1.4142135623730951;
    m[i] = c ? 0.5 * m[i] : m[i];
    e[i] += c ? 1 : 0;
  }
  double mp1[4], y[4];
#pragma unroll
  for (int i = 0; i < 4; ++i) mp1[i] = m[i] + 1.0;
#pragma unroll
  for (int i = 0; i < 4; ++i) y[i] = __builtin_amdgcn_rcp(mp1[i]);
#pragma unroll
  for (int i = 0; i < 4; ++i) y[i] = fma(fma(-mp1[i], y[i], 1.0), y[i], y[i]);
  double r[4], t[4], p[4];
#pragma unroll
  for (int i = 0; i < 4; ++i) r[i] = (m[i] - 1.0) * y[i];
#pragma unroll
  for (int i = 0; i < 4; ++i) t[i] = r[i] * r[i];
#pragma unroll
  for (int i = 0; i < 4; ++i) p[i] = fma(0.07692307692307693, t[i], 0.09090909090909091);
#pragma unroll
  for (int i = 0; i < 4; ++i) p[i] = fma(p[i], t[i], 0.1111111111111111);
#pragma unroll
  for (int i = 0; i < 4; ++i) p[i] = fma(p[i], t[i], 0.14285714285714285);
#pragma unroll
  for (int i = 0; i < 4; ++i) p[i] = fma(p[i], t[i], 0.2);
#pragma unroll
  for (int i = 0; i < 4; ++i) p[i] = fma(p[i], t[i], 0.3333333333333333);
#pragma unroll
  for (int i = 0; i < 4; ++i) p[i] = fma(p[i], t[i], 1.0);
#pragma unroll
  for (int i = 0; i < 4; ++i)
    out[i] = (float)fma((double)e[i], 0.6931471805599453, 2.0 * (r[i] * p[i]));
}

// scalar CR log (used once per row in erfinv path)
__device__ __forceinline__ float log_cr(float x) {
  float in[4] = {x, x, x, x}, o[4];
  log4_cr(in, o);
  return o[0];
}

// XLA ErfInv f32 expander (Giles poly), log1p per ElementalIrEmitter::EmitLog1p
__device__ float erfinv_xla(float x) {
#pragma clang fp contract(off)
  float x2  = x * x;
  float nx2 = -x2;
  float l1p;
  if (fabsf(nx2) < 1e-4f) {
    l1p = (-0.5f * nx2 + 1.0f) * nx2;
  } else {
    l1p = log_cr(1.0f + nx2);
  }
  float w = -l1p;
  float p;
  if (w < 5.0f) {
    float ww = w - 2.5f;
    p = 2.81022636e-08f;
    p = p * ww + 3.43273939e-07f;
    p = p * ww + -3.5233877e-06f;
    p = p * ww + -4.39150654e-06f;
    p = p * ww + 0.00021858087f;
    p = p * ww + -0.00125372503f;
    p = p * ww + -0.00417768164f;
    p = p * ww + 0.246640727f;
    p = p * ww + 1.50140941f;
  } else {
    float ww = sqrtf(w) - 3.0f;
    p = -0.000200214257f;
    p = p * ww + 0.000100950558f;
    p = p * ww + 0.00134934322f;
    p = p * ww + -0.00367342844f;
    p = p * ww + 0.00573950773f;
    p = p * ww + -0.0076224613f;
    p = p * ww + 0.00943887047f;
    p = p * ww + 1.00167406f;
    p = p * ww + 2.83297682f;
  }
  return p * x;
}

__global__ __launch_bounds__(NTHREADS, 6)
void gumbel_topk_mask(const float* __restrict__ wfull,   // (B,C,2S) f32
                      const int*   __restrict__ attn,    // (B,C,S) i32
                      const int*   __restrict__ ids,     // (B,C,S) i32
                      int* __restrict__ out,             // 3x(B,C,S) i32 concat
                      uint32_t kg0, uint32_t kg1, uint32_t kn0, uint32_t kn1) {
#pragma clang fp contract(off)
  const int row  = blockIdx.x;
  const int t    = threadIdx.x;
  const int lane = t & 63;
  const int wid  = t >> 6;

  __shared__ __align__(16) uint32_t hist[2][256];
  __shared__ uint32_t wsum[4];
  __shared__ uint32_t prefix_s;
  __shared__ uint32_t remaining_s;
  __shared__ int      done_s;

  const size_t rbase = (size_t)row * SLEN;
  const size_t wbase = (size_t)row * (2 * SLEN);
  const int    base  = t * EPT;            // contiguous chunk per thread

  hist[0][t] = 0u;                         // pass-3 histogram (fused below)
  hist[1][t] = 0u;

  // ---- phase 1: vector loads + staged 4-wide key pipelines ----
  const float4* wv4 = (const float4*)(wfull + wbase + base);
  float4 w0 = wv4[0], w1 = wv4[1];
  const int4* av4 = (const int4*)(attn + rbase + base);
  int4 a0 = av4[0], a1 = av4[1];
  const int4* iv4 = (const int4*)(ids + rbase + base);   // prefetch for epilogue
  int4 i0 = iv4[0], i1 = iv4[1];
  int psum = a0.x + a0.y + a0.z + a0.w + a1.x + a1.y + a1.z + a1.w;

  float wl[EPT] = {w0.x, w0.y, w0.z, w0.w, w1.x, w1.y, w1.z, w1.w};
  uint32_t mloc[EPT];
#pragma unroll
  for (int g = 0; g < 2; ++g) {            // two groups of 4 elements
    uint32_t bits[4];
    tf4_bits(kg0, kg1, (uint32_t)(rbase + base + 4 * g), bits);
    float uu[4];
#pragma unroll
    for (int j = 0; j < 4; ++j) {
      float f = u01_from_bits(bits[j]);
      uu[j] = fmaxf(1.17549435e-38f, f * 1.0f + 1.17549435e-38f);
    }
    float l1[4];
    log4_cr(uu, l1);                       // log u
    float wm[4];
#pragma unroll
    for (int j = 0; j < 4; ++j) wm[j] = fmaxf(wl[4 * g + j], 1e-30f);
    float lw[4];
    log4_cr(wm, lw);                       // log w (independent: covers l1 tail)
    float nl1[4];
#pragma unroll
    for (int j = 0; j < 4; ++j) nl1[j] = -l1[j];
    float l2[4];
    log4_cr(nl1, l2);                      // log(-log u); gumbel g = -l2
#pragma unroll
    for (int j = 0; j < 4; ++j) {
      float key = (wl[4 * g + j] > 0.0f) ? (lw[j] + (-l2[j])) : -__builtin_inff();
      uint32_t kb = __float_as_uint(key);
      uint32_t mv = (kb & 0x80000000u) ? ~kb : (kb | 0x80000000u);  // monotone
      mloc[4 * g + j] = mv;
    }
  }

  // attention-sum: wave reduce, one LDS slot per wave
#pragma unroll
  for (int off = 32; off; off >>= 1) psum += __shfl_down(psum, off, 64);
  if (lane == 0) wsum[wid] = (uint32_t)psum;
  if (t == 0) { prefix_s = 0u; done_s = 0; }
  __syncthreads();                         // hist zeroed, wsum/prefix ready

  // fused radix pass-3 histogram (unpredicated)
#pragma unroll
  for (int e = 0; e < EPT; ++e) atomicAdd(&hist[0][mloc[e] >> 24], 1u);

  // ---- radix-select k-th largest; ping-pong hist, 2 barriers/pass ----
  int cur = 0;
  for (int p = 3; p >= 0; --p) {
    __syncthreads();                       // pass-p atomics complete
    if (t < 64) {                          // wave 0: bin selection
      uint32_t need = 0u;
      if (p == 3) {
        int asum = (int)(wsum[0] + wsum[1] + wsum[2] + wsum[3]);
        uint32_t o0, o1;
        tf2x32(kn0, kn1, 0u, (uint32_t)row, o0, o1);   // all 64 lanes, same val
        float f   = u01_from_bits(o0 ^ o1);
        float lo  = __uint_as_float(0xBF7FFFFFu);      // nextafter(-1,0)
        float u2  = fmaxf(lo, f * 2.0f + lo);          // (1-lo) rounds to 2.0f
        float z   = erfinv_xla(u2);
        float nrm = 1.4142135623730951f * z;
        float frac = 0.15f + 0.0375f * nrm;
        int kk = (int)floorf((float)asum * frac);
        if (kk <= 0)         { if (t == 0) { prefix_s = 0xFFFFFFFFu; remaining_s = 0u;   done_s = 1; } }
        else if (kk >= SLEN) { if (t == 0) { prefix_s = 0u;          remaining_s = SLEN; done_s = 1; } }
        else need = (uint32_t)kk;
      } else {
        need = remaining_s;
      }
      if (need) {
        uint4 hq = ((const uint4*)hist[cur])[t];       // bins 4t..4t+3
        uint32_t gs  = hq.x + hq.y + hq.z + hq.w;
        uint32_t sfx = gs;                             // inclusive suffix sum
#pragma unroll
        for (int off = 1; off < 64; off <<= 1) {
          uint32_t n = __shfl_down(sfx, off, 64);
          if (t + off < 64) sfx += n;
        }
        uint32_t Gex = sfx - gs;                       // sum over lanes > t
        uint32_t S3 = Gex;
        uint32_t S2 = S3 + hq.w;
        uint32_t S1 = S2 + hq.z;
        uint32_t S0 = S1 + hq.y;
        uint32_t hh[4] = {hq.x, hq.y, hq.z, hq.w};
        uint32_t SS[4] = {S0, S1, S2, S3};
#pragma unroll
        for (int i = 0; i < 4; ++i) {
          if (hh[i] && SS[i] < need && need <= SS[i] + hh[i]) {   // unique winner
            prefix_s |= ((uint32_t)(4 * t + i)) << (8 * p);
            uint32_t rem = need - SS[i];
            remaining_s = rem;
            if (rem == hh[i]) done_s = 1;   // whole bin taken: low bytes stay 0
          }
        }
      }
    } else {                               // waves 1-3: clear the other buffer
      int idx = t - 64;
      hist[cur ^ 1][idx] = 0u;
      if (idx < 64) hist[cur ^ 1][idx + 192] = 0u;
    }
    __syncthreads();                       // prefix/remaining/done visible
    if (done_s) break;
    if (p > 0) {                           // predicated atomics for pass p-1
      uint32_t pref = prefix_s;
      int sh = 8 * p;
#pragma unroll
      for (int e = 0; e < EPT; ++e) {
        uint32_t m = mloc[e];
        if ((m >> sh) == (pref >> sh))
          atomicAdd(&hist[cur ^ 1][(m >> (sh - 8)) & 255u], 1u);
      }
    }
    cur ^= 1;
  }
  uint32_t T = prefix_s;
  uint32_t r = remaining_s;                // take first r (by index) among == T

  // ---- epilogue: stable tie-break scan + masked writes ----
  int local_eq = 0;
#pragma unroll
  for (int e = 0; e < EPT; ++e) local_eq += (mloc[e] == T) ? 1 : 0;
  uint32_t v = (uint32_t)local_eq;
#pragma unroll
  for (int off = 1; off < 64; off <<= 1) {
    uint32_t n = __shfl_up(v, off, 64);
    if (lane >= off) v += n;
  }
  if (lane == 63) wsum[wid] = v;
  __syncthreads();
  uint32_t add = 0;
  for (int i = 0; i < wid; ++i) add += wsum[i];
  uint32_t excl = add + v - (uint32_t)local_eq;   // #eq before my chunk

  int idv[EPT] = {i0.x, i0.y, i0.z, i0.w, i1.x, i1.y, i1.z, i1.w};
  int oid[EPT], omk[EPT], olb[EPT];
#pragma unroll
  for (int e = 0; e < EPT; ++e) {
    uint32_t m = mloc[e];
    bool eq  = (m == T);
    bool msk = (m > T) || (eq && (excl < r));
    excl += eq ? 1u : 0u;
    oid[e] = msk ? 103 : idv[e];      // MASK_ID
    omk[e] = msk ? 1 : 0;
    olb[e] = msk ? -1 : 0;
  }
  int4* po = (int4*)(out + rbase + base);
  po[0] = make_int4(oid[0], oid[1], oid[2], oid[3]);
  po[1] = make_int4(oid[4], oid[5], oid[6], oid[7]);
  int4* pm = (int4*)(out + TOKENS_PER_OUT + rbase + base);
  pm[0] = make_int4(omk[0], omk[1], omk[2], omk[3]);
  pm[1] = make_int4(omk[4], omk[5], omk[6], omk[7]);
  int4* pl = (int4*)(out + 2 * TOKENS_PER_OUT + rbase + base);
  pl[0] = make_int4(olb[0], olb[1], olb[2], olb[3]);
  pl[1] = make_int4(olb[4], olb[5], olb[6], olb[7]);
}

extern "C" void kernel_launch(void* const* d_in, const int* in_sizes, int n_in,
                              void* d_out, int out_size, void* d_ws, size_t ws_size,
                              hipStream_t stream) {
  (void)n_in; (void)d_ws; (void)ws_size; (void)out_size;
  const float* wfull = (const float*)d_in[0];   // my_attention_mask (B,C,2S)
  const int*   attn  = (const int*)d_in[1];     // attention_mask    (B,C,S)
  const int*   ids   = (const int*)d_in[2];     // input_ids         (B,C,S)
  int* out = (int*)d_out;

  // jax.random.key(42) -> (0,42); partitionable split: kg=enc(key,(0,0)), kn=enc(key,(0,1))
  uint32_t kg0, kg1, kn0, kn1, o0, o1;
  tf2x32(0u, 42u, 0u, 0u, o0, o1); kg0 = o0; kg1 = o1;
  tf2x32(0u, 42u, 0u, 1u, o0, o1); kn0 = o0; kn1 = o1;

  int rows = in_sizes[1] / SLEN;                // 4096
  hipLaunchKernelGGL(gumbel_topk_mask, dim3(rows), dim3(NTHREADS), 0, stream,
                     wfull, attn, ids, out, kg0, kg1, kn0, kn1);
}

// Round 6
// 202.329 us; speedup vs baseline: 1.0514x; 1.0254x over previous
//
#include <hip/hip_runtime.h>
#include <stdint.h>
#include <math.h>

#define SLEN 2048
#define EPT 8
#define NTHREADS 256
#define TOKENS_PER_OUT 8388608   // 1024*4*2048

// ---------- Threefry-2x32, 20 rounds, matches jax._src.prng ----------
__host__ __device__ __forceinline__ void tf2x32(uint32_t k0, uint32_t k1,
                                                uint32_t x0, uint32_t x1,
                                                uint32_t &o0, uint32_t &o1) {
  uint32_t ks2 = 0x1BD11BDAu ^ k0 ^ k1;
  x0 += k0; x1 += k1;
#define TFR(r) { x0 += x1; x1 = (x1 << (r)) | (x1 >> (32 - (r))); x1 ^= x0; }
  TFR(13) TFR(15) TFR(26) TFR(6)
  x0 += k1;  x1 += ks2 + 1u;
  TFR(17) TFR(29) TFR(16) TFR(24)
  x0 += ks2; x1 += k0 + 2u;
  TFR(13) TFR(15) TFR(26) TFR(6)
  x0 += k0;  x1 += k1 + 3u;
  TFR(17) TFR(29) TFR(16) TFR(24)
  x0 += k1;  x1 += ks2 + 4u;
  TFR(13) TFR(15) TFR(26) TFR(6)
  x0 += ks2; x1 += k0 + 5u;
#undef TFR
  o0 = x0; o1 = x1;
}

// 4 independent threefry streams; sched_barrier after each round keeps the
// 4-wide interleave intact through the machine scheduler.
__device__ __forceinline__ void tf4_bits(uint32_t k0, uint32_t k1,
                                         uint32_t cbase, uint32_t bits[4]) {
  const uint32_t ks2 = 0x1BD11BDAu ^ k0 ^ k1;
  uint32_t x0[4], x1[4];
#pragma unroll
  for (int i = 0; i < 4; ++i) { x0[i] = k0; x1[i] = (cbase + (uint32_t)i) + k1; }
#define TFR4(r)                                                         \
  _Pragma("unroll")                                                     \
  for (int i = 0; i < 4; ++i) {                                         \
    x0[i] += x1[i];                                                     \
    x1[i] = (x1[i] << (r)) | (x1[i] >> (32 - (r)));                     \
    x1[i] ^= x0[i];                                                     \
  }                                                                     \
  __builtin_amdgcn_sched_barrier(0);
#define INJ4(a, b)                                                      \
  _Pragma("unroll")                                                     \
  for (int i = 0; i < 4; ++i) { x0[i] += (a); x1[i] += (b); }
  TFR4(13) TFR4(15) TFR4(26) TFR4(6)
  INJ4(k1, ks2 + 1u)
  TFR4(17) TFR4(29) TFR4(16) TFR4(24)
  INJ4(ks2, k0 + 2u)
  TFR4(13) TFR4(15) TFR4(26) TFR4(6)
  INJ4(k0, k1 + 3u)
  TFR4(17) TFR4(29) TFR4(16) TFR4(24)
  INJ4(k1, ks2 + 4u)
  TFR4(13) TFR4(15) TFR4(26) TFR4(6)
  INJ4(ks2, k0 + 5u)
#undef TFR4
#undef INJ4
#pragma unroll
  for (int i = 0; i < 4; ++i) bits[i] = x0[i] ^ x1[i];
}

__device__ __forceinline__ float u01_from_bits(uint32_t bits) {
  return __uint_as_float((bits >> 9) | 0x3F800000u) - 1.0f;
}

#define SBAR() __builtin_amdgcn_sched_barrier(0)

// 8 correctly-rounded-quality f32 logs (positive normal f32 inputs), staged
// 8-wide with hard sched barriers so dependent f64 ops sit ~8 instrs apart.
// Values are BIT-IDENTICAL to the verified scalar math of R3-R5:
//   x = 2^e * m, m in [sqrt2/2, sqrt2)  (normalization done on the f32 bits:
//   mant > 0x3504F3  <=>  1.mant > sqrt2_f64, exact for 23-bit mantissas),
//   r = (m-1)*rcp(m+1) w/ 1 Newton, log = e*ln2 + 2r*(1 + t/3 + .. + t^6/13).
__device__ __forceinline__ void log8_cr(const float x[8], float out[8]) {
#pragma clang fp contract(off)
  double m[8]; int e[8];
#pragma unroll
  for (int i = 0; i < 8; ++i) {
    uint32_t xb   = __float_as_uint(x[i]);
    uint32_t mant = xb & 0x7FFFFFu;
    int      ee   = (int)(xb >> 23) - 127;
    bool     big  = mant > 0x3504F3u;          // m > sqrt(2)
    e[i] = ee + (big ? 1 : 0);
    uint32_t hi = (big ? 0x3FE00000u : 0x3FF00000u) | (mant >> 3);
    uint32_t lo = mant << 29;
    m[i] = __longlong_as_double(((long long)hi << 32) | (long long)lo);
  }
  SBAR();
  double mp1[8];
#pragma unroll
  for (int i = 0; i < 8; ++i) mp1[i] = m[i] + 1.0;
  SBAR();
  double y[8];
#pragma unroll
  for (int i = 0; i < 8; ++i) y[i] = __builtin_amdgcn_rcp(mp1[i]);
  SBAR();
#pragma unroll
  for (int i = 0; i < 8; ++i) y[i] = fma(fma(-mp1[i], y[i], 1.0), y[i], y[i]);
  SBAR();
  double r[8];
#pragma unroll
  for (int i = 0; i < 8; ++i) r[i] = (m[i] - 1.0) * y[i];
  SBAR();
  double t[8];
#pragma unroll
  for (int i = 0; i < 8; ++i) t[i] = r[i] * r[i];
  SBAR();
  double p[8];
#pragma unroll
  for (int i = 0; i < 8; ++i) p[i] = fma(0.07692307692307693, t[i], 0.09090909090909091);
  SBAR();
#pragma unroll
  for (int i = 0; i < 8; ++i) p[i] = fma(p[i], t[i], 0.1111111111111111);
  SBAR();
#pragma unroll
  for (int i = 0; i < 8; ++i) p[i] = fma(p[i], t[i], 0.14285714285714285);
  SBAR();
#pragma unroll
  for (int i = 0; i < 8; ++i) p[i] = fma(p[i], t[i], 0.2);
  SBAR();
#pragma unroll
  for (int i = 0; i < 8; ++i) p[i] = fma(p[i], t[i], 0.3333333333333333);
  SBAR();
#pragma unroll
  for (int i = 0; i < 8; ++i) p[i] = fma(p[i], t[i], 1.0);
  SBAR();
#pragma unroll
  for (int i = 0; i < 8; ++i) r[i] = r[i] + r[i];       // 2r (exact)
  SBAR();
#pragma unroll
  for (int i = 0; i < 8; ++i) p[i] = r[i] * p[i];       // 2r*q
  SBAR();
#pragma unroll
  for (int i = 0; i < 8; ++i)
    out[i] = (float)fma((double)e[i], 0.6931471805599453, p[i]);
}

// scalar CR log (erfinv path only; same math, unstaged)
__device__ __forceinline__ float log_cr(float x) {
#pragma clang fp contract(off)
  uint32_t xb   = __float_as_uint(x);
  uint32_t mant = xb & 0x7FFFFFu;
  int      e    = (int)(xb >> 23) - 127;
  bool     big  = mant > 0x3504F3u;
  e += big ? 1 : 0;
  uint32_t hi = (big ? 0x3FE00000u : 0x3FF00000u) | (mant >> 3);
  double m = __longlong_as_double(((long long)hi << 32) | (long long)(mant << 29));
  double mp1 = m + 1.0;
  double y = __builtin_amdgcn_rcp(mp1);
  y = fma(fma(-mp1, y, 1.0), y, y);
  double r = (m - 1.0) * y;
  double t = r * r;
  double p = fma(0.07692307692307693, t, 0.09090909090909091);
  p = fma(p, t, 0.1111111111111111);
  p = fma(p, t, 0.14285714285714285);
  p = fma(p, t, 0.2);
  p = fma(p, t, 0.3333333333333333);
  p = fma(p, t, 1.0);
  return (float)fma((double)e, 0.6931471805599453, (r + r) * p);
}

// XLA ErfInv f32 expander (Giles poly), log1p per ElementalIrEmitter::EmitLog1p
__device__ float erfinv_xla(float x) {
#pragma clang fp contract(off)
  float x2  = x * x;
  float nx2 = -x2;
  float l1p;
  if (fabsf(nx2) < 1e-4f) {
    l1p = (-0.5f * nx2 + 1.0f) * nx2;
  } else {
    l1p = log_cr(1.0f + nx2);
  }
  float w = -l1p;
  float p;
  if (w < 5.0f) {
    float ww = w - 2.5f;
    p = 2.81022636e-08f;
    p = p * ww + 3.43273939e-07f;
    p = p * ww + -3.5233877e-06f;
    p = p * ww + -4.39150654e-06f;
    p = p * ww + 0.00021858087f;
    p = p * ww + -0.00125372503f;
    p = p * ww + -0.00417768164f;
    p = p * ww + 0.246640727f;
    p = p * ww + 1.50140941f;
  } else {
    float ww = sqrtf(w) - 3.0f;
    p = -0.000200214257f;
    p = p * ww + 0.000100950558f;
    p = p * ww + 0.00134934322f;
    p = p * ww + -0.00367342844f;
    p = p * ww + 0.00573950773f;
    p = p * ww + -0.0076224613f;
    p = p * ww + 0.00943887047f;
    p = p * ww + 1.00167406f;
    p = p * ww + 2.83297682f;
  }
  return p * x;
}

__global__ __launch_bounds__(NTHREADS, 5)
void gumbel_topk_mask(const float* __restrict__ wfull,   // (B,C,2S) f32
                      const int*   __restrict__ attn,    // (B,C,S) i32
                      const int*   __restrict__ ids,     // (B,C,S) i32
                      int* __restrict__ out,             // 3x(B,C,S) i32 concat
                      uint32_t kg0, uint32_t kg1, uint32_t kn0, uint32_t kn1) {
#pragma clang fp contract(off)
  const int row  = blockIdx.x;
  const int t    = threadIdx.x;
  const int lane = t & 63;
  const int wid  = t >> 6;

  __shared__ __align__(16) uint32_t hist[2][256];
  __shared__ uint32_t wsum[4];
  __shared__ uint32_t prefix_s;
  __shared__ uint32_t remaining_s;
  __shared__ int      done_s;

  const size_t rbase = (size_t)row * SLEN;
  const size_t wbase = (size_t)row * (2 * SLEN);
  const int    base  = t * EPT;            // contiguous chunk per thread

  hist[0][t] = 0u;                         // pass-3 histogram (fused below)
  hist[1][t] = 0u;

  // ---- phase 1: vector loads + forced-ILP 8-wide key pipeline ----
  const float4* wv4 = (const float4*)(wfull + wbase + base);
  float4 w0 = wv4[0], w1 = wv4[1];
  const int4* av4 = (const int4*)(attn + rbase + base);
  int4 a0 = av4[0], a1 = av4[1];
  int psum = a0.x + a0.y + a0.z + a0.w + a1.x + a1.y + a1.z + a1.w;

  uint32_t bits[EPT];
  tf4_bits(kg0, kg1, (uint32_t)(rbase + base + 0), bits + 0);
  tf4_bits(kg0, kg1, (uint32_t)(rbase + base + 4), bits + 4);
  SBAR();

  float wl[EPT] = {w0.x, w0.y, w0.z, w0.w, w1.x, w1.y, w1.z, w1.w};
  float uu[EPT];
#pragma unroll
  for (int e = 0; e < EPT; ++e) {
    float f = u01_from_bits(bits[e]);
    uu[e] = fmaxf(1.17549435e-38f, f * 1.0f + 1.17549435e-38f);
  }
  SBAR();
  float l1[EPT];
  log8_cr(uu, l1);                         // log u
  float wm[EPT];
#pragma unroll
  for (int e = 0; e < EPT; ++e) wm[e] = fmaxf(wl[e], 1e-30f);
  float lw[EPT];
  log8_cr(wm, lw);                         // log w
  float nl1[EPT];
#pragma unroll
  for (int e = 0; e < EPT; ++e) nl1[e] = -l1[e];
  float l2[EPT];
  log8_cr(nl1, l2);                        // log(-log u); gumbel = -l2
  SBAR();
  uint32_t mloc[EPT];
#pragma unroll
  for (int e = 0; e < EPT; ++e) {
    float key = (wl[e] > 0.0f) ? (lw[e] + (-l2[e])) : -__builtin_inff();
    uint32_t kb = __float_as_uint(key);
    mloc[e] = (kb & 0x80000000u) ? ~kb : (kb | 0x80000000u);  // monotone map
  }

  // ids prefetch for epilogue (issued after the register-hungry pipeline)
  const int4* iv4 = (const int4*)(ids + rbase + base);
  int4 i0 = iv4[0], i1 = iv4[1];

  // attention-sum: wave reduce, one LDS slot per wave
#pragma unroll
  for (int off = 32; off; off >>= 1) psum += __shfl_down(psum, off, 64);
  if (lane == 0) wsum[wid] = (uint32_t)psum;
  if (t == 0) { prefix_s = 0u; done_s = 0; }
  __syncthreads();                         // hist zeroed, wsum/prefix ready

  // fused radix pass-3 histogram (unpredicated)
#pragma unroll
  for (int e = 0; e < EPT; ++e) atomicAdd(&hist[0][mloc[e] >> 24], 1u);

  // ---- radix-select k-th largest; ping-pong hist, 2 barriers/pass ----
  int cur = 0;
  for (int p = 3; p >= 0; --p) {
    __syncthreads();                       // pass-p atomics complete
    if (t < 64) {                          // wave 0: bin selection
      uint32_t need = 0u;
      if (p == 3) {
        int asum = (int)(wsum[0] + wsum[1] + wsum[2] + wsum[3]);
        uint32_t o0, o1;
        tf2x32(kn0, kn1, 0u, (uint32_t)row, o0, o1);   // all 64 lanes, same val
        float f   = u01_from_bits(o0 ^ o1);
        float lo  = __uint_as_float(0xBF7FFFFFu);      // nextafter(-1,0)
        float u2  = fmaxf(lo, f * 2.0f + lo);          // (1-lo) rounds to 2.0f
        float z   = erfinv_xla(u2);
        float nrm = 1.4142135623730951f * z;
        float frac = 0.15f + 0.0375f * nrm;
        int kk = (int)floorf((float)asum * frac);
        if (kk <= 0)         { if (t == 0) { prefix_s = 0xFFFFFFFFu; remaining_s = 0u;   done_s = 1; } }
        else if (kk >= SLEN) { if (t == 0) { prefix_s = 0u;          remaining_s = SLEN; done_s = 1; } }
        else need = (uint32_t)kk;
      } else {
        need = remaining_s;
      }
      if (need) {
        uint4 hq = ((const uint4*)hist[cur])[t];       // bins 4t..4t+3
        uint32_t gs  = hq.x + hq.y + hq.z + hq.w;
        uint32_t sfx = gs;                             // inclusive suffix sum
#pragma unroll
        for (int off = 1; off < 64; off <<= 1) {
          uint32_t n = __shfl_down(sfx, off, 64);
          if (t + off < 64) sfx += n;
        }
        uint32_t Gex = sfx - gs;                       // sum over lanes > t
        uint32_t S3 = Gex;
        uint32_t S2 = S3 + hq.w;
        uint32_t S1 = S2 + hq.z;
        uint32_t S0 = S1 + hq.y;
        uint32_t hh[4] = {hq.x, hq.y, hq.z, hq.w};
        uint32_t SS[4] = {S0, S1, S2, S3};
#pragma unroll
        for (int i = 0; i < 4; ++i) {
          if (hh[i] && SS[i] < need && need <= SS[i] + hh[i]) {   // unique winner
            prefix_s |= ((uint32_t)(4 * t + i)) << (8 * p);
            uint32_t rem = need - SS[i];
            remaining_s = rem;
            if (rem == hh[i]) done_s = 1;   // whole bin taken: low bytes stay 0
          }
        }
      }
    } else {                               // waves 1-3: clear the other buffer
      int idx = t - 64;
      hist[cur ^ 1][idx] = 0u;
      if (idx < 64) hist[cur ^ 1][idx + 192] = 0u;
    }
    __syncthreads();                       // prefix/remaining/done visible
    if (done_s) break;
    if (p > 0) {                           // predicated atomics for pass p-1
      uint32_t pref = prefix_s;
      int sh = 8 * p;
#pragma unroll
      for (int e = 0; e < EPT; ++e) {
        uint32_t m = mloc[e];
        if ((m >> sh) == (pref >> sh))
          atomicAdd(&hist[cur ^ 1][(m >> (sh - 8)) & 255u], 1u);
      }
    }
    cur ^= 1;
  }
  uint32_t T = prefix_s;
  uint32_t r = remaining_s;                // take first r (by index) among == T

  // ---- epilogue: stable tie-break scan + masked writes ----
  int local_eq = 0;
#pragma unroll
  for (int e = 0; e < EPT; ++e) local_eq += (mloc[e] == T) ? 1 : 0;
  uint32_t v = (uint32_t)local_eq;
#pragma unroll
  for (int off = 1; off < 64; off <<= 1) {
    uint32_t n = __shfl_up(v, off, 64);
    if (lane >= off) v += n;
  }
  if (lane == 63) wsum[wid] = v;
  __syncthreads();
  uint32_t add = 0;
  for (int i = 0; i < wid; ++i) add += wsum[i];
  uint32_t excl = add + v - (uint32_t)local_eq;   // #eq before my chunk

  int idv[EPT] = {i0.x, i0.y, i0.z, i0.w, i1.x, i1.y, i1.z, i1.w};
  int oid[EPT], omk[EPT], olb[EPT];
#pragma unroll
  for (int e = 0; e < EPT; ++e) {
    uint32_t m = mloc[e];
    bool eq  = (m == T);
    bool msk = (m > T) || (eq && (excl < r));
    excl += eq ? 1u : 0u;
    oid[e] = msk ? 103 : idv[e];      // MASK_ID
    omk[e] = msk ? 1 : 0;
    olb[e] = msk ? -1 : 0;
  }
  int4* po = (int4*)(out + rbase + base);
  po[0] = make_int4(oid[0], oid[1], oid[2], oid[3]);
  po[1] = make_int4(oid[4], oid[5], oid[6], oid[7]);
  int4* pm = (int4*)(out + TOKENS_PER_OUT + rbase + base);
  pm[0] = make_int4(omk[0], omk[1], omk[2], omk[3]);
  pm[1] = make_int4(omk[4], omk[5], omk[6], omk[7]);
  int4* pl = (int4*)(out + 2 * TOKENS_PER_OUT + rbase + base);
  pl[0] = make_int4(olb[0], olb[1], olb[2], olb[3]);
  pl[1] = make_int4(olb[4], olb[5], olb[6], olb[7]);
}

extern "C" void kernel_launch(void* const* d_in, const int* in_sizes, int n_in,
                              void* d_out, int out_size, void* d_ws, size_t ws_size,
                              hipStream_t stream) {
  (void)n_in; (void)d_ws; (void)ws_size; (void)out_size;
  const float* wfull = (const float*)d_in[0];   // my_attention_mask (B,C,2S)
  const int*   attn  = (const int*)d_in[1];     // attention_mask    (B,C,S)
  const int*   ids   = (const int*)d_in[2];     // input_ids         (B,C,S)
  int* out = (int*)d_out;

  // jax.random.key(42) -> (0,42); partitionable split: kg=enc(key,(0,0)), kn=enc(key,(0,1))
  uint32_t kg0, kg1, kn0, kn1, o0, o1;
  tf2x32(0u, 42u, 0u, 0u, o0, o1); kg0 = o0; kg1 = o1;
  tf2x32(0u, 42u, 0u, 1u, o0, o1); kn0 = o0; kn1 = o1;

  int rows = in_sizes[1] / SLEN;                // 4096
  hipLaunchKernelGGL(gumbel_topk_mask, dim3(rows), dim3(NTHREADS), 0, stream,
                     wfull, attn, ids, out, kg0, kg1, kn0, kn1);
}